// Round 1
// 344.569 us; speedup vs baseline: 1.1048x; 1.1048x over previous
//
#include <hip/hip_runtime.h>
#include <hip/hip_fp16.h>

#define B_  32
#define L_  2048
#define H_  512
#define CA  64        // chunk size (was 32): halves the serial chunk chain
#define NC  32        // chunks per batch; key row l=2047 zero-padded
#define EPSF 1e-6f

typedef _Float16 f16x8 __attribute__((ext_vector_type(8)));
typedef float f32x16 __attribute__((ext_vector_type(16)));

// ---- wave64 sum reduction via DPP; full sum lands in lane 63 ----
template <int CTRL>
__device__ __forceinline__ float dpp_shift_add(float x) {
  int t = __builtin_amdgcn_update_dpp(0, __float_as_int(x), CTRL, 0xf, 0xf, true);
  return x + __int_as_float(t);
}
__device__ __forceinline__ float wave_reduce_lane63(float x) {
  x = dpp_shift_add<0x111>(x);  // row_shr:1
  x = dpp_shift_add<0x112>(x);  // row_shr:2
  x = dpp_shift_add<0x114>(x);  // row_shr:4
  x = dpp_shift_add<0x118>(x);  // row_shr:8
  x = dpp_shift_add<0x142>(x);  // row_bcast:15
  x = dpp_shift_add<0x143>(x);  // row_bcast:31
  return x;                     // valid in lane 63
}
__device__ __forceinline__ float rdlane(float v, int l) {
  return __int_as_float(__builtin_amdgcn_readlane(__float_as_int(v), l));
}
// async global->LDS, 16B per lane; LDS base must be wave-uniform
__device__ __forceinline__ void load_lds16h(const unsigned short* g, unsigned short* l) {
  __builtin_amdgcn_global_load_lds(
      (const __attribute__((address_space(1))) unsigned int*)(g),
      (__attribute__((address_space(3))) unsigned int*)(l), 16, 0, 0);
}

// =====================================================================
// Kernel A: per (batch, 64-chunk):
//  - round keys to fp16, write Kh (row-major [t][h]) to global
//  - keep fp16 copy in LDS, granule-transposed [k8][row] (16B granules)
//    so 32x32x16 f16 MFMA fragments are single conflict-free ds_read_b128
//  - Gram G = K~ K~^T via 3 MFMA tiles (00,01,11); dvec = diag(G)+eps
//  - X = (D + triu(G,1))^{-1} via two 32x32 backsubs + Schur block:
//    X = [[X00, -X00 U12 X11],[0, X11]]
//  - tmT flat[s*64+j] = X[s][j]  (row-major X)
// grid (NC, B_), 256 threads (4 waves). LDS = 64KB + 16KB = 80KiB exactly.
// =====================================================================
__global__ __launch_bounds__(256) void
deltarule_gram64(const float* __restrict__ hidden,
                 unsigned short* __restrict__ Kh,
                 float* __restrict__ tmT, float* __restrict__ dvec) {
  const int cb = blockIdx.x, b = blockIdx.y;
  const int tid = threadIdx.x, lane = tid & 63, wv = tid >> 6;
  __shared__ __align__(16) unsigned short Kf[CA * H_];  // 64 KB fp16, granule-transposed
  __shared__ __align__(16) float G[CA * CA];            // 16 KB

  const int c0 = cb * CA;
  const float* src = hidden + ((size_t)b * L_ + c0) * H_;
  unsigned short* kout = Kh + ((size_t)b * L_ + c0) * H_;
  const bool lastc = (cb == NC - 1);

  // ---- stage + round to fp16: thread handles 8-float groups ----
  // f8 = u*256+tid indexes groups of 8 floats; row = f8>>6, colf = (f8&63)*8
#pragma unroll
  for (int u = 0; u < 16; ++u) {
    const int f8 = u * 256 + tid;
    const int row = f8 >> 6;
    const int colf = (f8 & 63) * 8;
    float4 va = *(const float4*)(src + row * H_ + colf);
    float4 vb = *(const float4*)(src + row * H_ + colf + 4);
    if (lastc && row == CA - 1) {   // zero-pad key row l=2047
      va = make_float4(0.f, 0.f, 0.f, 0.f);
      vb = make_float4(0.f, 0.f, 0.f, 0.f);
    }
    __half2 h0 = __floats2half2_rn(va.x, va.y);
    __half2 h1 = __floats2half2_rn(va.z, va.w);
    __half2 h2 = __floats2half2_rn(vb.x, vb.y);
    __half2 h3 = __floats2half2_rn(vb.z, vb.w);
    uint4 pk = make_uint4(*(unsigned int*)&h0, *(unsigned int*)&h1,
                          *(unsigned int*)&h2, *(unsigned int*)&h3);
    // LDS granule-transposed: granule (k8=colf>>3, row), 16B each
    *(uint4*)&Kf[((colf >> 3) * CA + row) * 8] = pk;
    // global row-major fp16 (feeds the scan's DMA)
    *(uint4*)(kout + row * H_ + colf) = pk;
  }
  __syncthreads();

  // ---- Gram via MFMA: waves 0,1,2 -> tiles (0,0),(0,1),(1,1) ----
  if (wv < 3) {
    const int ta = (wv == 2) ? 1 : 0;
    const int tb = (wv == 0) ? 0 : 1;
    const int mrow = 32 * ta + (lane & 31);
    const int nrow = 32 * tb + (lane & 31);
    const int khi = lane >> 5;
    f32x16 acc;
#pragma unroll
    for (int r = 0; r < 16; ++r) acc[r] = 0.f;
#pragma unroll
    for (int kk = 0; kk < 32; ++kk) {
      const int k8 = 2 * kk + khi;
      const f16x8 av = *(const f16x8*)&Kf[(k8 * CA + mrow) * 8];
      const f16x8 bv = *(const f16x8*)&Kf[(k8 * CA + nrow) * 8];
      acc = __builtin_amdgcn_mfma_f32_32x32x16_f16(av, bv, acc, 0, 0, 0);
    }
#pragma unroll
    for (int r = 0; r < 16; ++r) {
      const int row32 = (r & 3) + 8 * (r >> 2) + 4 * khi;
      G[(32 * ta + row32) * CA + 32 * tb + (lane & 31)] = acc[r];
    }
  }
  __syncthreads();

  // ---- dvec = diag(G)+eps (must read diag before backsub overwrites) ----
  if (tid < CA) dvec[((size_t)b * NC + cb) * CA + tid] = G[tid * CA + tid] + EPSF;
  __syncthreads();

  // ---- two parallel 32x32 backsubs: wave0 -> X00, wave1 -> X11 ----
  if (wv == 0) {
    const int j = lane & 31;
    float X[32];
#pragma unroll
    for (int t = 31; t >= 0; --t) {
      float i0 = 0.f, i1 = 0.f;
#pragma unroll
      for (int s = t + 1; s < 32; s += 2) i0 = fmaf(G[t * CA + s], X[s], i0);
#pragma unroll
      for (int s = t + 2; s < 32; s += 2) i1 = fmaf(G[t * CA + s], X[s], i1);
      X[t] = (((j == t) ? 1.f : 0.f) - (i0 + i1)) / (G[t * CA + t] + EPSF);
    }
    if (lane < 32) {
#pragma unroll
      for (int t = 0; t < 32; ++t) G[t * CA + j] = X[t];   // X00 over U00
    }
  } else if (wv == 1) {
    const int j = lane & 31;
    float X[32];
#pragma unroll
    for (int t = 31; t >= 0; --t) {
      float i0 = 0.f, i1 = 0.f;
#pragma unroll
      for (int s = t + 1; s < 32; s += 2) i0 = fmaf(G[(32 + t) * CA + 32 + s], X[s], i0);
#pragma unroll
      for (int s = t + 2; s < 32; s += 2) i1 = fmaf(G[(32 + t) * CA + 32 + s], X[s], i1);
      X[t] = (((j == t) ? 1.f : 0.f) - (i0 + i1)) / (G[(32 + t) * CA + 32 + t] + EPSF);
    }
    if (lane < 32) {
#pragma unroll
      for (int t = 0; t < 32; ++t) G[(32 + t) * CA + 32 + j] = X[t];  // X11 over U11
    }
  }
  __syncthreads();

  // ---- Schur: Z = U12 * X11 (regs), then Y = -X00 * Z over the U12 slot ----
  const int zr = tid >> 3;          // 0..31
  const int zc = (tid & 7) * 4;     // 0..28
  float4 zf = make_float4(0.f, 0.f, 0.f, 0.f);
#pragma unroll
  for (int s = 0; s < 32; ++s) {
    const float u = G[zr * CA + 32 + s];                      // U12[zr][s]
    const float4 xv = *(const float4*)&G[(32 + s) * CA + 32 + zc];  // X11[s][zc..]
    zf.x = fmaf(u, xv.x, zf.x); zf.y = fmaf(u, xv.y, zf.y);
    zf.z = fmaf(u, xv.z, zf.z); zf.w = fmaf(u, xv.w, zf.w);
  }
  __syncthreads();                  // all U12 reads done
  *(float4*)&G[zr * CA + 32 + zc] = zf;
  __syncthreads();                  // Z visible
  float4 yf = make_float4(0.f, 0.f, 0.f, 0.f);
#pragma unroll
  for (int s = 0; s < 32; ++s) {
    const float u = G[zr * CA + s];                           // X00[zr][s]
    const float4 zv = *(const float4*)&G[s * CA + 32 + zc];   // Z[s][zc..]
    yf.x = fmaf(u, zv.x, yf.x); yf.y = fmaf(u, zv.y, yf.y);
    yf.z = fmaf(u, zv.z, yf.z); yf.w = fmaf(u, zv.w, yf.w);
  }
  __syncthreads();                  // all Z reads done
  *(float4*)&G[zr * CA + 32 + zc] = make_float4(-yf.x, -yf.y, -yf.z, -yf.w);
  __syncthreads();

  // ---- write out tmT flat[s*64+j] = X[s][j]; lower-left block = 0 ----
  float* tout = tmT + ((size_t)b * NC + cb) * (CA * CA);
#pragma unroll
  for (int v = 0; v < 4; ++v) {
    const int f4 = v * 256 + tid;
    const int s = f4 >> 4;
    const int j4 = (f4 & 15) * 4;
    float4 val;
    if (s >= 32 && j4 < 32) val = make_float4(0.f, 0.f, 0.f, 0.f);
    else                    val = *(const float4*)&G[s * CA + j4];
    *(float4*)(tout + s * CA + j4) = val;
  }
}

// =====================================================================
// Kernel B: backward chunked scan + fused output GEMM, CA=64 (32 serial
// steps). grid (B_), 512 threads (8 waves). One row-major fp16 K chunk in
// LDS serves both the dot (ds_read_b128 rows, conflict-free) and the
// update (ds_read_u16 column h=tid, 2B/lane consecutive, conflict-free).
// Double-buffered DMA; per-thread X prefetch is 2 x b128 (tmT row-major).
// =====================================================================
__global__ __launch_bounds__(512) void
deltarule_scan64(const float* __restrict__ hidden,
                 const unsigned short* __restrict__ Kh,
                 const float* __restrict__ Wm, const float* __restrict__ bias,
                 const float* __restrict__ tmT, const float* __restrict__ dvec,
                 float* __restrict__ out) {
  const int b = blockIdx.x, tid = threadIdx.x, lane = tid & 63, wv = tid >> 6;
  __shared__ __align__(16) unsigned short KT[2][CA * H_];  // 2 x 64 KB
  __shared__ float Part[8 * CA];                           // 2 KB sigma partials
  __shared__ __align__(16) float Wv[H_];
  __shared__ __align__(16) float Ctx[H_];

  const unsigned short* khb = Kh + (size_t)b * L_ * H_;
  const float* tmb = tmT + (size_t)b * NC * (CA * CA);
  const float* dvb = dvec + (size_t)b * NC * CA;

  float wh = hidden[((size_t)b * L_ + (L_ - 1)) * H_ + tid];  // query
  Wv[tid] = wh;
  float ch = 0.f;

  // ---- preloop: stage chunk NC-1 -> KT[1]; prefetch its X rows / d ----
  {
    const unsigned short* s0 = khb + (size_t)(NC - 1) * CA * H_;
#pragma unroll
    for (int u = 0; u < 8; ++u) {
      const int off = (u * 8 + wv) * 512;
      load_lds16h(s0 + off + 8 * lane, &KT[(NC - 1) & 1][off]);
    }
  }
  float4 tA, tB; float dCur;
  {
    const float* tp = tmb + (size_t)(NC - 1) * (CA * CA) + lane * CA + 8 * wv;
    tA = *(const float4*)tp;
    tB = *(const float4*)(tp + 4);
    dCur = dvb[(NC - 1) * CA + lane];
  }
  asm volatile("s_waitcnt vmcnt(0) lgkmcnt(0)\n\ts_barrier" ::: "memory");

  for (int c = NC - 1; c >= 0; --c) {
    const int buf = c & 1;

    // ---- prefetch chunk c-1 regs + DMA chunk c-1 into other buffer ----
    float4 nA, nB; float dN = 0.f;
    if (c > 0) {
      const float* tp = tmb + (size_t)(c - 1) * (CA * CA) + lane * CA + 8 * wv;
      nA = *(const float4*)tp;
      nB = *(const float4*)(tp + 4);
      dN = dvb[(c - 1) * CA + lane];
      const unsigned short* s1 = khb + (size_t)(c - 1) * CA * H_;
#pragma unroll
      for (int u = 0; u < 8; ++u) {
        const int off = (u * 8 + wv) * 512;
        load_lds16h(s1 + off + 8 * lane, &KT[buf ^ 1][off]);
      }
    }

    // ---- dot: y[8wv+i] = K~[row] . w  (rows from LDS, lane-consecutive) ----
    const float4 wa  = *(const float4*)&Wv[8 * lane];
    const float4 wb2 = *(const float4*)&Wv[8 * lane + 4];
    float ysg[8];
#pragma unroll
    for (int i = 0; i < 8; ++i) {
      const uint4 kr = *(const uint4*)&KT[buf][(8 * wv + i) * H_ + 8 * lane];
      const float2 f0 = __half22float2(*(const __half2*)&kr.x);
      const float2 f1 = __half22float2(*(const __half2*)&kr.y);
      const float2 f2 = __half22float2(*(const __half2*)&kr.z);
      const float2 f3 = __half22float2(*(const __half2*)&kr.w);
      float p = f0.x * wa.x;
      p = fmaf(f0.y, wa.y, p); p = fmaf(f1.x, wa.z, p); p = fmaf(f1.y, wa.w, p);
      p = fmaf(f2.x, wb2.x, p); p = fmaf(f2.y, wb2.y, p);
      p = fmaf(f3.x, wb2.z, p); p = fmaf(f3.y, wb2.w, p);
      p = wave_reduce_lane63(p);
      ysg[i] = rdlane(p, 63);
    }

    // ---- sigma partial: sp[j=lane] = sum_i y[8wv+i] * X[j][8wv+i] ----
    float sp = ysg[0] * tA.x;
    sp = fmaf(ysg[1], tA.y, sp); sp = fmaf(ysg[2], tA.z, sp);
    sp = fmaf(ysg[3], tA.w, sp); sp = fmaf(ysg[4], tB.x, sp);
    sp = fmaf(ysg[5], tB.y, sp); sp = fmaf(ysg[6], tB.z, sp);
    sp = fmaf(ysg[7], tB.w, sp);
    Part[wv * CA + lane] = sp;
    asm volatile("s_waitcnt lgkmcnt(0)\n\ts_barrier" ::: "memory");  // b1

    // ---- combine partials; s = D * sigma ----
    float sig = Part[lane];
#pragma unroll
    for (int w2 = 1; w2 < 8; ++w2) sig += Part[w2 * CA + lane];
    const float sv = dCur * sig;

    // ---- update: w -= K^T sigma ; ctx += K^T s  (h = tid, column via LDS) ----
    float dw0 = 0.f, dw1 = 0.f, dc0 = 0.f, dc1 = 0.f;
#pragma unroll
    for (int t = 0; t < CA; t += 2) {
      const float kv0 = __half2float(*(const __half*)&KT[buf][t * H_ + tid]);
      const float kv1 = __half2float(*(const __half*)&KT[buf][(t + 1) * H_ + tid]);
      dw0 = fmaf(rdlane(sig, t), kv0, dw0);
      dc0 = fmaf(rdlane(sv, t), kv0, dc0);
      dw1 = fmaf(rdlane(sig, t + 1), kv1, dw1);
      dc1 = fmaf(rdlane(sv, t + 1), kv1, dc1);
    }
    wh -= dw0 + dw1;
    ch += dc0 + dc1;
    Wv[tid] = wh;

    // rotate prefetched regs
    if (c > 0) { dCur = dN; tA = nA; tB = nB; }
    // b_end: DMA issued ~a full iteration ago -> vmcnt(0) is cheap here
    asm volatile("s_waitcnt vmcnt(0) lgkmcnt(0)\n\ts_barrier" ::: "memory");
  }

  // ---- epilogue: out[b] = W @ ctx + bias ----
  Ctx[tid] = ch;
  __syncthreads();
  float acc = bias[tid];
  const float* wr = Wm + (size_t)tid * H_;
#pragma unroll 8
  for (int i = 0; i < H_; i += 4) {
    const float4 w4 = *(const float4*)(wr + i);
    const float4 cv = *(const float4*)&Ctx[i];
    acc = fmaf(w4.x, cv.x, acc); acc = fmaf(w4.y, cv.y, acc);
    acc = fmaf(w4.z, cv.z, acc); acc = fmaf(w4.w, cv.w, acc);
  }
  out[(size_t)b * H_ + tid] = acc;
}

// =====================================================================
extern "C" void kernel_launch(void* const* d_in, const int* in_sizes, int n_in,
                              void* d_out, int out_size, void* d_ws, size_t ws_size,
                              hipStream_t stream) {
  (void)in_sizes; (void)n_in; (void)out_size; (void)ws_size;
  const float* hidden = (const float*)d_in[0];  // (32, 2048, 512) fp32
  const float* Wm     = (const float*)d_in[1];  // (512, 512) fp32
  const float* bias   = (const float*)d_in[2];  // (512,) fp32
  float* out = (float*)d_out;                   // (32, 512) fp32

  // workspace: Kh 64 MB + tmT 16 MB + dvec 256 KB = 80.25 MB (was 136.25)
  const size_t szKh = (size_t)B_ * L_ * H_ * sizeof(unsigned short);
  unsigned short* Kh = (unsigned short*)d_ws;
  float* tmT  = (float*)((char*)d_ws + szKh);
  float* dvec = tmT + (size_t)B_ * NC * CA * CA;

  deltarule_gram64<<<dim3(NC, B_), 256, 0, stream>>>(hidden, Kh, tmT, dvec);
  deltarule_scan64<<<B_, 512, 0, stream>>>(hidden, Kh, Wm, bias, tmT, dvec, out);
}

// Round 2
// 340.998 us; speedup vs baseline: 1.1164x; 1.0105x over previous
//
#include <hip/hip_runtime.h>
#include <hip/hip_fp16.h>

#define B_  32
#define L_  2048
#define H_  512
#define CA  64        // chunk size; 32 serial steps per batch
#define NC  32        // chunks per batch; key row l=2047 zero-padded
#define EPSF 1e-6f

typedef _Float16 f16x8 __attribute__((ext_vector_type(8)));
typedef float f32x16 __attribute__((ext_vector_type(16)));

// ---- wave64 sum reduction via DPP; full sum lands in lane 63 ----
template <int CTRL>
__device__ __forceinline__ float dpp_shift_add(float x) {
  int t = __builtin_amdgcn_update_dpp(0, __float_as_int(x), CTRL, 0xf, 0xf, true);
  return x + __int_as_float(t);
}
__device__ __forceinline__ float wave_reduce_lane63(float x) {
  x = dpp_shift_add<0x111>(x);  // row_shr:1
  x = dpp_shift_add<0x112>(x);  // row_shr:2
  x = dpp_shift_add<0x114>(x);  // row_shr:4
  x = dpp_shift_add<0x118>(x);  // row_shr:8
  x = dpp_shift_add<0x142>(x);  // row_bcast:15
  x = dpp_shift_add<0x143>(x);  // row_bcast:31
  return x;                     // valid in lane 63
}
__device__ __forceinline__ float rdlane(float v, int l) {
  return __int_as_float(__builtin_amdgcn_readlane(__float_as_int(v), l));
}
// async global->LDS, 16B per lane; LDS base must be wave-uniform
__device__ __forceinline__ void load_lds16h(const unsigned short* g, unsigned short* l) {
  __builtin_amdgcn_global_load_lds(
      (const __attribute__((address_space(1))) unsigned int*)(g),
      (__attribute__((address_space(3))) unsigned int*)(l), 16, 0, 0);
}

// =====================================================================
// Kernel A (unchanged from round 1): per (batch, 64-chunk):
//  - round keys to fp16, write Kh (row-major [t][h]) to global
//  - Gram G = K~ K~^T via 3 MFMA tiles; dvec = diag(G)+eps
//  - X = (D + triu(G,1))^{-1} via two 32x32 backsubs + Schur block
//  - tmT flat[s*64+j] = X[s][j]  (row-major X)
// grid (NC, B_), 256 threads (4 waves). LDS = 80 KiB.
// =====================================================================
__global__ __launch_bounds__(256) void
deltarule_gram64(const float* __restrict__ hidden,
                 unsigned short* __restrict__ Kh,
                 float* __restrict__ tmT, float* __restrict__ dvec) {
  const int cb = blockIdx.x, b = blockIdx.y;
  const int tid = threadIdx.x, lane = tid & 63, wv = tid >> 6;
  __shared__ __align__(16) unsigned short Kf[CA * H_];  // 64 KB fp16, granule-transposed
  __shared__ __align__(16) float G[CA * CA];            // 16 KB

  const int c0 = cb * CA;
  const float* src = hidden + ((size_t)b * L_ + c0) * H_;
  unsigned short* kout = Kh + ((size_t)b * L_ + c0) * H_;
  const bool lastc = (cb == NC - 1);

  // ---- stage + round to fp16: thread handles 8-float groups ----
#pragma unroll
  for (int u = 0; u < 16; ++u) {
    const int f8 = u * 256 + tid;
    const int row = f8 >> 6;
    const int colf = (f8 & 63) * 8;
    float4 va = *(const float4*)(src + row * H_ + colf);
    float4 vb = *(const float4*)(src + row * H_ + colf + 4);
    if (lastc && row == CA - 1) {   // zero-pad key row l=2047
      va = make_float4(0.f, 0.f, 0.f, 0.f);
      vb = make_float4(0.f, 0.f, 0.f, 0.f);
    }
    __half2 h0 = __floats2half2_rn(va.x, va.y);
    __half2 h1 = __floats2half2_rn(va.z, va.w);
    __half2 h2 = __floats2half2_rn(vb.x, vb.y);
    __half2 h3 = __floats2half2_rn(vb.z, vb.w);
    uint4 pk = make_uint4(*(unsigned int*)&h0, *(unsigned int*)&h1,
                          *(unsigned int*)&h2, *(unsigned int*)&h3);
    *(uint4*)&Kf[((colf >> 3) * CA + row) * 8] = pk;
    *(uint4*)(kout + row * H_ + colf) = pk;
  }
  __syncthreads();

  // ---- Gram via MFMA: waves 0,1,2 -> tiles (0,0),(0,1),(1,1) ----
  if (wv < 3) {
    const int ta = (wv == 2) ? 1 : 0;
    const int tb = (wv == 0) ? 0 : 1;
    const int mrow = 32 * ta + (lane & 31);
    const int nrow = 32 * tb + (lane & 31);
    const int khi = lane >> 5;
    f32x16 acc;
#pragma unroll
    for (int r = 0; r < 16; ++r) acc[r] = 0.f;
#pragma unroll
    for (int kk = 0; kk < 32; ++kk) {
      const int k8 = 2 * kk + khi;
      const f16x8 av = *(const f16x8*)&Kf[(k8 * CA + mrow) * 8];
      const f16x8 bv = *(const f16x8*)&Kf[(k8 * CA + nrow) * 8];
      acc = __builtin_amdgcn_mfma_f32_32x32x16_f16(av, bv, acc, 0, 0, 0);
    }
#pragma unroll
    for (int r = 0; r < 16; ++r) {
      const int row32 = (r & 3) + 8 * (r >> 2) + 4 * khi;
      G[(32 * ta + row32) * CA + 32 * tb + (lane & 31)] = acc[r];
    }
  }
  __syncthreads();

  // ---- dvec = diag(G)+eps ----
  if (tid < CA) dvec[((size_t)b * NC + cb) * CA + tid] = G[tid * CA + tid] + EPSF;
  __syncthreads();

  // ---- two parallel 32x32 backsubs: wave0 -> X00, wave1 -> X11 ----
  if (wv == 0) {
    const int j = lane & 31;
    float X[32];
#pragma unroll
    for (int t = 31; t >= 0; --t) {
      float i0 = 0.f, i1 = 0.f;
#pragma unroll
      for (int s = t + 1; s < 32; s += 2) i0 = fmaf(G[t * CA + s], X[s], i0);
#pragma unroll
      for (int s = t + 2; s < 32; s += 2) i1 = fmaf(G[t * CA + s], X[s], i1);
      X[t] = (((j == t) ? 1.f : 0.f) - (i0 + i1)) / (G[t * CA + t] + EPSF);
    }
    if (lane < 32) {
#pragma unroll
      for (int t = 0; t < 32; ++t) G[t * CA + j] = X[t];   // X00 over U00
    }
  } else if (wv == 1) {
    const int j = lane & 31;
    float X[32];
#pragma unroll
    for (int t = 31; t >= 0; --t) {
      float i0 = 0.f, i1 = 0.f;
#pragma unroll
      for (int s = t + 1; s < 32; s += 2) i0 = fmaf(G[(32 + t) * CA + 32 + s], X[s], i0);
#pragma unroll
      for (int s = t + 2; s < 32; s += 2) i1 = fmaf(G[(32 + t) * CA + 32 + s], X[s], i1);
      X[t] = (((j == t) ? 1.f : 0.f) - (i0 + i1)) / (G[(32 + t) * CA + 32 + t] + EPSF);
    }
    if (lane < 32) {
#pragma unroll
      for (int t = 0; t < 32; ++t) G[(32 + t) * CA + 32 + j] = X[t];  // X11 over U11
    }
  }
  __syncthreads();

  // ---- Schur: Z = U12 * X11 (regs), then Y = -X00 * Z over the U12 slot ----
  const int zr = tid >> 3;          // 0..31
  const int zc = (tid & 7) * 4;     // 0..28
  float4 zf = make_float4(0.f, 0.f, 0.f, 0.f);
#pragma unroll
  for (int s = 0; s < 32; ++s) {
    const float u = G[zr * CA + 32 + s];
    const float4 xv = *(const float4*)&G[(32 + s) * CA + 32 + zc];
    zf.x = fmaf(u, xv.x, zf.x); zf.y = fmaf(u, xv.y, zf.y);
    zf.z = fmaf(u, xv.z, zf.z); zf.w = fmaf(u, xv.w, zf.w);
  }
  __syncthreads();
  *(float4*)&G[zr * CA + 32 + zc] = zf;
  __syncthreads();
  float4 yf = make_float4(0.f, 0.f, 0.f, 0.f);
#pragma unroll
  for (int s = 0; s < 32; ++s) {
    const float u = G[zr * CA + s];
    const float4 zv = *(const float4*)&G[s * CA + 32 + zc];
    yf.x = fmaf(u, zv.x, yf.x); yf.y = fmaf(u, zv.y, yf.y);
    yf.z = fmaf(u, zv.z, yf.z); yf.w = fmaf(u, zv.w, yf.w);
  }
  __syncthreads();
  *(float4*)&G[zr * CA + 32 + zc] = make_float4(-yf.x, -yf.y, -yf.z, -yf.w);
  __syncthreads();

  // ---- write out tmT flat[s*64+j] = X[s][j]; lower-left block = 0 ----
  float* tout = tmT + ((size_t)b * NC + cb) * (CA * CA);
#pragma unroll
  for (int v = 0; v < 4; ++v) {
    const int f4 = v * 256 + tid;
    const int s = f4 >> 4;
    const int j4 = (f4 & 15) * 4;
    float4 val;
    if (s >= 32 && j4 < 32) val = make_float4(0.f, 0.f, 0.f, 0.f);
    else                    val = *(const float4*)&G[s * CA + j4];
    *(float4*)(tout + s * CA + j4) = val;
  }
}

// =====================================================================
// Kernel B v4: 1024 threads (16 waves, 4 waves/SIMD) for latency hiding.
// Dot: 4 rows/wave (LDS row-major b128). Update group-split:
//   waves 0-7  (tid<512):  w[h]  -= sum_t sig[t] K[t][h]   (h = tid)
//   waves 8-15 (tid>=512): ctx[h]+= sum_t sv[t]  K[t][h]   (h = tid-512)
// ctx accumulates in registers; combined only at the end. 2 barriers/step.
// =====================================================================
__global__ __launch_bounds__(1024) void
deltarule_scan64w(const float* __restrict__ hidden,
                  const unsigned short* __restrict__ Kh,
                  const float* __restrict__ Wm, const float* __restrict__ bias,
                  const float* __restrict__ tmT, const float* __restrict__ dvec,
                  float* __restrict__ out) {
  const int b = blockIdx.x, tid = threadIdx.x, lane = tid & 63, wv = tid >> 6;
  __shared__ __align__(16) unsigned short KT[2][CA * H_];  // 128 KB
  __shared__ __align__(16) float Part[16 * 64];            // 4 KB (reused in epilogue)
  __shared__ __align__(16) float Wv[H_];
  __shared__ __align__(16) float Ctx[H_];

  const unsigned short* khb = Kh + (size_t)b * L_ * H_;
  const float* tmb = tmT + (size_t)b * NC * (CA * CA);
  const float* dvb = dvec + (size_t)b * NC * CA;

  const int hh = tid & (H_ - 1);
  const bool wgroup = (tid < H_);
  float wh = 0.f, ch = 0.f;
  if (wgroup) {
    wh = hidden[((size_t)b * L_ + (L_ - 1)) * H_ + tid];  // query
    Wv[tid] = wh;
  }

  // ---- preloop: stage chunk NC-1 -> KT[1]; prefetch its X rows / d ----
  {
    const unsigned short* s0 = khb + (size_t)(NC - 1) * CA * H_;
#pragma unroll
    for (int u = 0; u < 4; ++u) {
      const int off = (u * 16 + wv) * 512;
      load_lds16h(s0 + off + 8 * lane, &KT[(NC - 1) & 1][off]);
    }
  }
  float4 tA; float dCur;
  {
    tA = *(const float4*)(tmb + (size_t)(NC - 1) * (CA * CA) + lane * CA + 4 * wv);
    dCur = dvb[(NC - 1) * CA + lane];
  }
  asm volatile("s_waitcnt vmcnt(0) lgkmcnt(0)\n\ts_barrier" ::: "memory");

  for (int c = NC - 1; c >= 0; --c) {
    const int buf = c & 1;

    // ---- prefetch chunk c-1 regs + DMA chunk c-1 into other buffer ----
    float4 nA; float dN = 0.f;
    if (c > 0) {
      nA = *(const float4*)(tmb + (size_t)(c - 1) * (CA * CA) + lane * CA + 4 * wv);
      dN = dvb[(c - 1) * CA + lane];
      const unsigned short* s1 = khb + (size_t)(c - 1) * CA * H_;
#pragma unroll
      for (int u = 0; u < 4; ++u) {
        const int off = (u * 16 + wv) * 512;
        load_lds16h(s1 + off + 8 * lane, &KT[buf ^ 1][off]);
      }
    }
    asm volatile("" ::: "memory");

    // ---- dot: y[4wv+i] = K~[row] . w ; rows from LDS (b128, stride-1) ----
    const float4 wa  = *(const float4*)&Wv[8 * lane];
    const float4 wb2 = *(const float4*)&Wv[8 * lane + 4];
    float ysg[4];
#pragma unroll
    for (int i = 0; i < 4; ++i) {
      const uint4 kr = *(const uint4*)&KT[buf][(4 * wv + i) * H_ + 8 * lane];
      const __half* kh = (const __half*)&kr;
      float p =            __half2float(kh[0]) * wa.x;
      p = fmaf(__half2float(kh[1]), wa.y, p);
      p = fmaf(__half2float(kh[2]), wa.z, p);
      p = fmaf(__half2float(kh[3]), wa.w, p);
      p = fmaf(__half2float(kh[4]), wb2.x, p);
      p = fmaf(__half2float(kh[5]), wb2.y, p);
      p = fmaf(__half2float(kh[6]), wb2.z, p);
      p = fmaf(__half2float(kh[7]), wb2.w, p);
      p = wave_reduce_lane63(p);
      ysg[i] = rdlane(p, 63);
    }

    // ---- sigma partial: sp[j=lane] = sum_i y[4wv+i] * X[j][4wv+i] ----
    float sp = ysg[0] * tA.x;
    sp = fmaf(ysg[1], tA.y, sp);
    sp = fmaf(ysg[2], tA.z, sp);
    sp = fmaf(ysg[3], tA.w, sp);
    Part[wv * 64 + lane] = sp;
    asm volatile("s_waitcnt lgkmcnt(0)\n\ts_barrier" ::: "memory");  // b1

    // ---- combine 16 partials; per-group scale ----
    float sig = Part[lane];
#pragma unroll
    for (int w2 = 1; w2 < 16; ++w2) sig += Part[w2 * 64 + lane];
    const float src = wgroup ? sig : dCur * sig;   // sig for w, sv=D*sig for ctx

    // ---- update: own h = hh; column read (u16, conflict-free) ----
    const unsigned short* kcol = &KT[buf][0] + hh;
    float a0 = 0.f, a1 = 0.f, a2 = 0.f, a3 = 0.f;
#pragma unroll
    for (int t = 0; t < CA; t += 4) {
      a0 = fmaf(rdlane(src, t + 0), __half2float(*(const __half*)&kcol[(t + 0) * H_]), a0);
      a1 = fmaf(rdlane(src, t + 1), __half2float(*(const __half*)&kcol[(t + 1) * H_]), a1);
      a2 = fmaf(rdlane(src, t + 2), __half2float(*(const __half*)&kcol[(t + 2) * H_]), a2);
      a3 = fmaf(rdlane(src, t + 3), __half2float(*(const __half*)&kcol[(t + 3) * H_]), a3);
    }
    const float upd = (a0 + a1) + (a2 + a3);
    if (wgroup) { wh -= upd; Wv[tid] = wh; }
    else        { ch += upd; }

    // rotate prefetched regs
    if (c > 0) { dCur = dN; tA = nA; }
    asm volatile("s_waitcnt vmcnt(0) lgkmcnt(0)\n\ts_barrier" ::: "memory");  // b_end
  }

  // ---- epilogue: out[b] = W @ ctx + bias (split dot over 2 halves) ----
  if (!wgroup) Ctx[hh] = ch;
  __syncthreads();
  {
    const int o = hh, hf = tid >> 9;
    float acc = 0.f;
    const float* wr = Wm + (size_t)o * H_ + hf * 256;
    const float* cx = &Ctx[hf * 256];
#pragma unroll 8
    for (int i = 0; i < 256; i += 4) {
      const float4 w4 = *(const float4*)(wr + i);
      const float4 cv = *(const float4*)(cx + i);
      acc = fmaf(w4.x, cv.x, acc); acc = fmaf(w4.y, cv.y, acc);
      acc = fmaf(w4.z, cv.z, acc); acc = fmaf(w4.w, cv.w, acc);
    }
    Part[hf * 512 + o] = acc;
  }
  __syncthreads();
  if (wgroup) out[(size_t)b * H_ + tid] = Part[tid] + Part[512 + tid] + bias[tid];
}

// =====================================================================
extern "C" void kernel_launch(void* const* d_in, const int* in_sizes, int n_in,
                              void* d_out, int out_size, void* d_ws, size_t ws_size,
                              hipStream_t stream) {
  (void)in_sizes; (void)n_in; (void)out_size; (void)ws_size;
  const float* hidden = (const float*)d_in[0];  // (32, 2048, 512) fp32
  const float* Wm     = (const float*)d_in[1];  // (512, 512) fp32
  const float* bias   = (const float*)d_in[2];  // (512,) fp32
  float* out = (float*)d_out;                   // (32, 512) fp32

  // workspace: Kh 64 MB + tmT 16 MB + dvec 256 KB
  const size_t szKh = (size_t)B_ * L_ * H_ * sizeof(unsigned short);
  unsigned short* Kh = (unsigned short*)d_ws;
  float* tmT  = (float*)((char*)d_ws + szKh);
  float* dvec = tmT + (size_t)B_ * NC * CA * CA;

  deltarule_gram64<<<dim3(NC, B_), 256, 0, stream>>>(hidden, Kh, tmT, dvec);
  deltarule_scan64w<<<B_, 1024, 0, stream>>>(hidden, Kh, Wm, bias, tmT, dvec, out);
}